// Round 3
// baseline (272.329 us; speedup 1.0000x reference)
//
#include <hip/hip_runtime.h>
#include <cstdint>
#include <cstddef>

#define IN_CH 128
#define HID_CH 128
#define OUT_CH 64
#define BSH 8        // nodes per bucket = 256
#define PB 4096      // edges per histogram/partition block

typedef unsigned int uint32;
typedef unsigned char uchar;
typedef short bf16x8 __attribute__((ext_vector_type(8)));
typedef float f32x4 __attribute__((ext_vector_type(4)));
typedef float f32x2 __attribute__((ext_vector_type(2)));

// float -> bf16 round-to-nearest-even
static __device__ __forceinline__ unsigned short f2bf(float f) {
    uint32 u = __float_as_uint(f);
    u += 0x7fffu + ((u >> 16) & 1u);
    return (unsigned short)(u >> 16);
}
// float -> fp8 e4m3 (OCP) single byte via HW cvt
static __device__ __forceinline__ uchar f2fp8(float f) {
    int p = __builtin_amdgcn_cvt_pk_fp8_f32(f, f, 0, false);
    return (uchar)(p & 0xff);
}

// ---------------- CSR build (bucketed, LDS-atomic only) ----------------

// bhist over buckets; wtrans fused into trailing blocks (independent work).
__global__ __launch_bounds__(256) void bhist_wtrans(
    const int* __restrict__ dst, int* __restrict__ bcnt, int E, int NB, int gP,
    const float* __restrict__ W1, const float* __restrict__ W2,
    unsigned short* __restrict__ W1t, unsigned short* __restrict__ W2t) {
    if (blockIdx.x >= (uint32)gP) {
        int t = (blockIdx.x - gP) * 256 + threadIdx.x;
        if (t < 128 * 128) {
            int nc = t >> 7, k = t & 127;
            W1t[t] = f2bf(W1[k * 128 + nc]);
        }
        int u = t - 128 * 128;
        if (u >= 0 && u < 64 * 128) {
            int nc = u >> 7, k = u & 127;
            W2t[u] = f2bf(W2[k * 64 + nc]);
        }
        return;
    }
    __shared__ int h[512];
    int t = threadIdx.x;
    int e0 = blockIdx.x * PB;
    int cnt = min(PB, E - e0);
    for (int b = t; b < NB; b += 256) h[b] = 0;
    __syncthreads();
    for (int i = t; i < cnt; i += 256)
        atomicAdd(&h[dst[e0 + i] >> BSH], 1);
    __syncthreads();
    for (int b = t; b < NB; b += 256)
        if (h[b]) atomicAdd(&bcnt[b], h[b]);
}

// cursors start at ZERO (part1 adds bbase[b] itself).
__global__ void bscan(const int* __restrict__ bcnt, int* __restrict__ bbase,
                      int* __restrict__ bcur, int NB, int E) {
    __shared__ int s[512];
    int t = threadIdx.x;
    int v = (t < NB) ? bcnt[t] : 0;
    s[t] = v;
    __syncthreads();
    for (int o = 1; o < 512; o <<= 1) {
        int add = (t >= o) ? s[t - o] : 0;
        __syncthreads();
        s[t] += add;
        __syncthreads();
    }
    if (t < NB) { bbase[t] = s[t] - v; bcur[t] = 0; }
    if (t == 0) bbase[NB] = E;
}

// part1: edges cached in LDS (single global read), histogram, then grouped write.
__global__ __launch_bounds__(256) void part1(
    const int* __restrict__ src, const int* __restrict__ dst,
    const int* __restrict__ bbase, int* __restrict__ bcur,
    int2* __restrict__ pairBuf, int E, int NB) {
    __shared__ int2 pairs[PB];          // 32 KB
    __shared__ int hist[512];
    __shared__ int base[512];
    int t = threadIdx.x;
    int e0 = blockIdx.x * PB;
    int cnt = min(PB, E - e0);
    for (int b = t; b < NB; b += 256) hist[b] = 0;
    __syncthreads();
    for (int i = t; i < cnt; i += 256) {
        int s = src[e0 + i], d = dst[e0 + i];
        pairs[i] = make_int2(s, d);
        atomicAdd(&hist[d >> BSH], 1);
    }
    __syncthreads();
    for (int b = t; b < NB; b += 256) {
        int h = hist[b];
        int gb = (h > 0) ? atomicAdd(&bcur[b], h) : 0;
        base[b] = bbase[b] + gb;
        hist[b] = 0;
    }
    __syncthreads();
    for (int i = t; i < cnt; i += 256) {
        int2 p = pairs[i];
        int b = p.y >> BSH;
        int q = base[b] + atomicAdd(&hist[b], 1);
        pairBuf[q] = p;
    }
}

__global__ __launch_bounds__(256) void bucket_build(
    const int2* __restrict__ pairBuf, const int* __restrict__ bbase,
    int* __restrict__ rowptr, int* __restrict__ deg, float* __restrict__ dinv,
    int* __restrict__ csr, int N) {
    __shared__ int cnt[256];
    __shared__ int loc[256];
    int b = blockIdx.x, t = threadIdx.x;
    int start = bbase[b], end = bbase[b + 1];
    cnt[t] = 0;
    __syncthreads();
    for (int i = start + t; i < end; i += 256)
        atomicAdd(&cnt[pairBuf[i].y & 255], 1);
    __syncthreads();
    int v = cnt[t];
    loc[t] = v;
    __syncthreads();
    for (int o = 1; o < 256; o <<= 1) {
        int add = (t >= o) ? loc[t - o] : 0;
        __syncthreads();
        loc[t] += add;
        __syncthreads();
    }
    int excl = loc[t] - v;
    int node = (b << BSH) + t;
    if (node < N) {
        rowptr[node] = start + excl;
        deg[node] = v;
        dinv[node] = rsqrtf((float)(v + 2));   // +2 self-loops
    }
    __syncthreads();
    cnt[t] = excl;                              // reuse as cursor
    __syncthreads();
    for (int i = start + t; i < end; i += 256) {
        int2 p = pairBuf[i];
        int q = start + atomicAdd(&cnt[p.y & 255], 1);
        csr[q] = p.x;
    }
}

// ---------------- MFMA GEMM: C[n,OUT] = dinv[n] * (A[n,128] @ W[128,OUT]) -> fp8 ----
// Fully barrier-free, zero-LDS streaming GEMM. One 16-row m-tile per wave:
//   - A fragments straight from global (8x float4 per lane, all independent ->
//     deep MLP; 16 rows x contiguous windows, coalesced, each line touched once).
//   - B fragments straight from global: W1t/W2t are 32/16 KB and live in L1
//     after first touch (G14: HW caches handle read-only data; no LDS needed).
//   - No __syncthreads anywhere, no VGPR cap: occupancy is VGPR-limited only
//     (~96-112 VGPR -> 4-5 waves/SIMD), waves never collectively stall.

template <int OUT, bool AFP32>
__global__ __launch_bounds__(256) void gemm_mfma(
    const void* __restrict__ Av, const unsigned short* __restrict__ Wt,
    const float* __restrict__ dinv, uchar* __restrict__ C, int n) {
    constexpr int NT = OUT / 16;

    const int t = threadIdx.x;
    const int w = t >> 6, l = t & 63;
    const int q = l >> 4, r16 = l & 15;
    const int row0 = blockIdx.x * 64 + w * 16;   // 16 rows per wave
    const int ra = row0 + r16;
    const int rac = min(ra, n - 1);

    f32x4 acc[NT];
#pragma unroll
    for (int i = 0; i < NT; i++) acc[i] = (f32x4){0.f, 0.f, 0.f, 0.f};

    // --- A fragments for all 4 K-steps, issued up-front (independent) ---
    bf16x8 afr[4];
    if (AFP32) {
        const float* A = (const float*)Av + (size_t)rac * 128;
        float4 v[8];
#pragma unroll
        for (int s = 0; s < 4; s++) {
            int k0 = s * 32 + q * 8;
            v[2 * s]     = *(const float4*)(A + k0);
            v[2 * s + 1] = *(const float4*)(A + k0 + 4);
        }
#pragma unroll
        for (int s = 0; s < 4; s++) {
            afr[s][0] = (short)f2bf(v[2 * s].x);     afr[s][1] = (short)f2bf(v[2 * s].y);
            afr[s][2] = (short)f2bf(v[2 * s].z);     afr[s][3] = (short)f2bf(v[2 * s].w);
            afr[s][4] = (short)f2bf(v[2 * s + 1].x); afr[s][5] = (short)f2bf(v[2 * s + 1].y);
            afr[s][6] = (short)f2bf(v[2 * s + 1].z); afr[s][7] = (short)f2bf(v[2 * s + 1].w);
        }
    } else {
        const unsigned short* A = (const unsigned short*)Av + (size_t)rac * 128;
#pragma unroll
        for (int s = 0; s < 4; s++)
            afr[s] = *(const bf16x8*)(A + s * 32 + q * 8);
    }

    // --- K-loop: B from L1-resident Wt, MFMA accumulate ---
#pragma unroll
    for (int s = 0; s < 4; s++) {
        const int k0 = s * 32 + q * 8;
#pragma unroll
        for (int nt = 0; nt < NT; nt++) {
            bf16x8 b = *(const bf16x8*)(Wt + (size_t)(nt * 16 + r16) * 128 + k0);
            acc[nt] = __builtin_amdgcn_mfma_f32_16x16x32_bf16(afr[s], b, acc[nt], 0, 0, 0);
        }
    }

    // --- epilogue: dinv pre-scale + fp8 store ---
    float dva[4];
#pragma unroll
    for (int p = 0; p < 4; p++) {
        int rr = row0 + q * 4 + p;
        dva[p] = (rr < n) ? dinv[rr] : 0.f;
    }
#pragma unroll
    for (int nt = 0; nt < NT; nt++) {
#pragma unroll
        for (int p = 0; p < 4; p++) {
            int rr = row0 + q * 4 + p;
            if (rr < n) C[(size_t)rr * OUT + nt * 16 + r16] = f2fp8(acc[nt][p] * dva[p]);
        }
    }
}

// ---------------- Aggregation: QUARTER-WAVE per node, UNWEIGHTED fp8 sum --------
// H rows arrive pre-scaled by dinv[src] (GEMM epilogue), so the edge loop is a
// pure gather+sum: no per-edge weight gathers/shuffles, f32x2 packed adds
// (v_pk_add_f32), 8 loads in flight per wave iteration.

// agg1: 128 ch, lane covers 8 ch (uint2 = 8 fp8). out = bf16.
__global__ __launch_bounds__(256) void agg_relu_128(
    const uchar* __restrict__ H, const int* __restrict__ csr,
    const int* __restrict__ rowptr, const int* __restrict__ deg,
    const float* __restrict__ dinv, const float* __restrict__ bias,
    unsigned short* __restrict__ out, int n) {
    int v = blockIdx.x * 16 + (threadIdx.x >> 4);
    int hl = threadIdx.x & 15;
    int gsel = threadIdx.x & 48;
    bool valid = v < n;
    int vc = valid ? v : 0;
    int base = rowptr[vc];
    int cnt = valid ? deg[vc] : 0;
    const uint32 co = (uint32)(hl * 8);

    f32x2 A0 = (f32x2){0.f, 0.f}, A1 = A0, A2 = A0, A3 = A0;
    f32x2 B0 = A0, B1 = A0, B2 = A0, B3 = A0;

#define ACC128(h, s0, s1, s2, s3)                                   \
    {                                                               \
        s0 += __builtin_amdgcn_cvt_pk_f32_fp8((h).x, false);        \
        s1 += __builtin_amdgcn_cvt_pk_f32_fp8((h).x, true);         \
        s2 += __builtin_amdgcn_cvt_pk_f32_fp8((h).y, false);        \
        s3 += __builtin_amdgcn_cvt_pk_f32_fp8((h).y, true);         \
    }

    for (int j0 = 0; j0 < cnt; j0 += 16) {
        int nj = min(16, cnt - j0);
        int ul = 0;
        if (hl < nj) ul = csr[base + j0 + hl];
        int j = 0;
        for (; j + 8 <= nj; j += 8) {
            int u0 = __shfl(ul, (j + 0) | gsel), u1 = __shfl(ul, (j + 1) | gsel);
            int u2 = __shfl(ul, (j + 2) | gsel), u3 = __shfl(ul, (j + 3) | gsel);
            int u4 = __shfl(ul, (j + 4) | gsel), u5 = __shfl(ul, (j + 5) | gsel);
            int u6 = __shfl(ul, (j + 6) | gsel), u7 = __shfl(ul, (j + 7) | gsel);
            uint2 h0 = *(const uint2*)(H + (((uint32)u0 << 7) + co));
            uint2 h1 = *(const uint2*)(H + (((uint32)u1 << 7) + co));
            uint2 h2 = *(const uint2*)(H + (((uint32)u2 << 7) + co));
            uint2 h3 = *(const uint2*)(H + (((uint32)u3 << 7) + co));
            uint2 h4 = *(const uint2*)(H + (((uint32)u4 << 7) + co));
            uint2 h5 = *(const uint2*)(H + (((uint32)u5 << 7) + co));
            uint2 h6 = *(const uint2*)(H + (((uint32)u6 << 7) + co));
            uint2 h7 = *(const uint2*)(H + (((uint32)u7 << 7) + co));
            ACC128(h0, A0, A1, A2, A3);
            ACC128(h1, B0, B1, B2, B3);
            ACC128(h2, A0, A1, A2, A3);
            ACC128(h3, B0, B1, B2, B3);
            ACC128(h4, A0, A1, A2, A3);
            ACC128(h5, B0, B1, B2, B3);
            ACC128(h6, A0, A1, A2, A3);
            ACC128(h7, B0, B1, B2, B3);
        }
        for (; j + 4 <= nj; j += 4) {
            int u0 = __shfl(ul, (j + 0) | gsel), u1 = __shfl(ul, (j + 1) | gsel);
            int u2 = __shfl(ul, (j + 2) | gsel), u3 = __shfl(ul, (j + 3) | gsel);
            uint2 h0 = *(const uint2*)(H + (((uint32)u0 << 7) + co));
            uint2 h1 = *(const uint2*)(H + (((uint32)u1 << 7) + co));
            uint2 h2 = *(const uint2*)(H + (((uint32)u2 << 7) + co));
            uint2 h3 = *(const uint2*)(H + (((uint32)u3 << 7) + co));
            ACC128(h0, A0, A1, A2, A3);
            ACC128(h1, B0, B1, B2, B3);
            ACC128(h2, A0, A1, A2, A3);
            ACC128(h3, B0, B1, B2, B3);
        }
        for (; j < nj; j++) {
            int u = __shfl(ul, j | gsel);
            uint2 h = *(const uint2*)(H + (((uint32)u << 7) + co));
            ACC128(h, A0, A1, A2, A3);
        }
    }
#undef ACC128

    if (valid) {
        float dv = dinv[vc];
        uint2 hv = *(const uint2*)(H + (((uint32)vc << 7) + co));
        f32x2 s0 = __builtin_amdgcn_cvt_pk_f32_fp8(hv.x, false);
        f32x2 s1 = __builtin_amdgcn_cvt_pk_f32_fp8(hv.x, true);
        f32x2 s2 = __builtin_amdgcn_cvt_pk_f32_fp8(hv.y, false);
        f32x2 s3 = __builtin_amdgcn_cvt_pk_f32_fp8(hv.y, true);
        const f32x2* bp = (const f32x2*)(bias + hl * 8);
        f32x2 e0 = dv * ((A0 + B0) + 2.f * s0) + bp[0];
        f32x2 e1 = dv * ((A1 + B1) + 2.f * s1) + bp[1];
        f32x2 e2 = dv * ((A2 + B2) + 2.f * s2) + bp[2];
        f32x2 e3 = dv * ((A3 + B3) + 2.f * s3) + bp[3];
        float o0 = fmaxf(e0[0], 0.f), o1 = fmaxf(e0[1], 0.f);
        float o2 = fmaxf(e1[0], 0.f), o3 = fmaxf(e1[1], 0.f);
        float o4 = fmaxf(e2[0], 0.f), o5 = fmaxf(e2[1], 0.f);
        float o6 = fmaxf(e3[0], 0.f), o7 = fmaxf(e3[1], 0.f);
        uint4 pk;
        pk.x = (uint32)f2bf(o0) | ((uint32)f2bf(o1) << 16);
        pk.y = (uint32)f2bf(o2) | ((uint32)f2bf(o3) << 16);
        pk.z = (uint32)f2bf(o4) | ((uint32)f2bf(o5) << 16);
        pk.w = (uint32)f2bf(o6) | ((uint32)f2bf(o7) << 16);
        *(uint4*)(out + (size_t)vc * 128 + hl * 8) = pk;
    }
}

// agg2: 64 ch, lane covers 4 ch (uint = 4 fp8). log_softmax within group of 16.
__global__ __launch_bounds__(256) void agg_lsm_64(
    const uchar* __restrict__ H, const int* __restrict__ csr,
    const int* __restrict__ rowptr, const int* __restrict__ deg,
    const float* __restrict__ dinv, const float* __restrict__ bias,
    float* __restrict__ out, int n) {
    int v = blockIdx.x * 16 + (threadIdx.x >> 4);
    int hl = threadIdx.x & 15;
    int gsel = threadIdx.x & 48;
    bool valid = v < n;
    int vc = valid ? v : 0;
    int base = rowptr[vc];
    int cnt = valid ? deg[vc] : 0;
    const uint32 co = (uint32)(hl * 4);

    f32x2 A0 = (f32x2){0.f, 0.f}, A1 = A0, B0 = A0, B1 = A0;

#define ACC64(h, s0, s1)                                            \
    {                                                               \
        s0 += __builtin_amdgcn_cvt_pk_f32_fp8((h), false);          \
        s1 += __builtin_amdgcn_cvt_pk_f32_fp8((h), true);           \
    }

    for (int j0 = 0; j0 < cnt; j0 += 16) {
        int nj = min(16, cnt - j0);
        int ul = 0;
        if (hl < nj) ul = csr[base + j0 + hl];
        int j = 0;
        for (; j + 8 <= nj; j += 8) {
            int u0 = __shfl(ul, (j + 0) | gsel), u1 = __shfl(ul, (j + 1) | gsel);
            int u2 = __shfl(ul, (j + 2) | gsel), u3 = __shfl(ul, (j + 3) | gsel);
            int u4 = __shfl(ul, (j + 4) | gsel), u5 = __shfl(ul, (j + 5) | gsel);
            int u6 = __shfl(ul, (j + 6) | gsel), u7 = __shfl(ul, (j + 7) | gsel);
            uint32 h0 = *(const uint32*)(H + (((uint32)u0 << 6) + co));
            uint32 h1 = *(const uint32*)(H + (((uint32)u1 << 6) + co));
            uint32 h2 = *(const uint32*)(H + (((uint32)u2 << 6) + co));
            uint32 h3 = *(const uint32*)(H + (((uint32)u3 << 6) + co));
            uint32 h4 = *(const uint32*)(H + (((uint32)u4 << 6) + co));
            uint32 h5 = *(const uint32*)(H + (((uint32)u5 << 6) + co));
            uint32 h6 = *(const uint32*)(H + (((uint32)u6 << 6) + co));
            uint32 h7 = *(const uint32*)(H + (((uint32)u7 << 6) + co));
            ACC64(h0, A0, A1);
            ACC64(h1, B0, B1);
            ACC64(h2, A0, A1);
            ACC64(h3, B0, B1);
            ACC64(h4, A0, A1);
            ACC64(h5, B0, B1);
            ACC64(h6, A0, A1);
            ACC64(h7, B0, B1);
        }
        for (; j + 4 <= nj; j += 4) {
            int u0 = __shfl(ul, (j + 0) | gsel), u1 = __shfl(ul, (j + 1) | gsel);
            int u2 = __shfl(ul, (j + 2) | gsel), u3 = __shfl(ul, (j + 3) | gsel);
            uint32 h0 = *(const uint32*)(H + (((uint32)u0 << 6) + co));
            uint32 h1 = *(const uint32*)(H + (((uint32)u1 << 6) + co));
            uint32 h2 = *(const uint32*)(H + (((uint32)u2 << 6) + co));
            uint32 h3 = *(const uint32*)(H + (((uint32)u3 << 6) + co));
            ACC64(h0, A0, A1);
            ACC64(h1, B0, B1);
            ACC64(h2, A0, A1);
            ACC64(h3, B0, B1);
        }
        for (; j < nj; j++) {
            int u = __shfl(ul, j | gsel);
            uint32 h = *(const uint32*)(H + (((uint32)u << 6) + co));
            ACC64(h, A0, A1);
        }
    }
#undef ACC64

    float dv = dinv[vc];
    uint32 hv = *(const uint32*)(H + (((uint32)vc << 6) + co));
    f32x2 s0 = __builtin_amdgcn_cvt_pk_f32_fp8(hv, false);
    f32x2 s1 = __builtin_amdgcn_cvt_pk_f32_fp8(hv, true);
    const f32x2* bp = (const f32x2*)(bias + hl * 4);
    f32x2 w0 = dv * ((A0 + B0) + 2.f * s0) + bp[0];
    f32x2 w1 = dv * ((A1 + B1) + 2.f * s1) + bp[1];
    float v0 = w0[0], v1 = w0[1], v2 = w1[0], v3 = w1[1];
    // log_softmax across the 64 channels held by this 16-lane group
    float m = fmaxf(fmaxf(v0, v1), fmaxf(v2, v3));
    for (int o = 8; o > 0; o >>= 1) m = fmaxf(m, __shfl_xor(m, o));
    float e = (__expf(v0 - m) + __expf(v1 - m)) + (__expf(v2 - m) + __expf(v3 - m));
    for (int o = 8; o > 0; o >>= 1) e += __shfl_xor(e, o);
    float ls = m + __logf(e);
    if (valid)
        *(float4*)(out + (size_t)vc * 64 + hl * 4) =
            make_float4(v0 - ls, v1 - ls, v2 - ls, v3 - ls);
}

// ---------------- launch ----------------

extern "C" void kernel_launch(void* const* d_in, const int* in_sizes, int n_in,
                              void* d_out, int out_size, void* d_ws, size_t ws_size,
                              hipStream_t stream) {
    const float* x  = (const float*)d_in[0];
    const int*   ei = (const int*)d_in[1];
    const float* W1 = (const float*)d_in[2];
    const float* b1 = (const float*)d_in[3];
    const float* W2 = (const float*)d_in[4];
    const float* b2 = (const float*)d_in[5];
    float* out = (float*)d_out;

    const int N = in_sizes[0] / IN_CH;  // 100000
    const int E = in_sizes[1] / 2;      // 1600000
    const int* src = ei;
    const int* dst = ei + E;
    const int NB = (N + 255) >> BSH;    // 391 buckets

    char* w = (char*)d_ws;
    size_t off = 0;
    auto alloc = [&](size_t bytes) -> char* {
        char* p = w + off;
        off = (off + bytes + 255) & ~(size_t)255;
        return p;
    };
    int*   deg    = (int*)alloc((size_t)N * 4);
    int*   rowptr = (int*)alloc((size_t)N * 4);
    int*   bcnt   = (int*)alloc(512 * 4);
    int*   bbase  = (int*)alloc(513 * 4);
    int*   bcur   = (int*)alloc(512 * 4);
    float* dinv   = (float*)alloc((size_t)N * 4);
    int*   csr    = (int*)alloc((size_t)E * 4);
    unsigned short* W1t = (unsigned short*)alloc(128 * 128 * 2);
    unsigned short* W2t = (unsigned short*)alloc(64 * 128 * 2);
    uchar* H1  = (uchar*)alloc((size_t)N * HID_CH);          // fp8, 12.8 MB
    unsigned short* A1b = (unsigned short*)alloc((size_t)N * HID_CH * 2);  // bf16
    uchar* H2  = H1;                     // fp8; H1 dead after agg1
    int2*  pairBuf = (int2*)A1b;         // A1b not written until agg1 (after bucket_build)

    hipMemsetAsync(bcnt, 0, 512 * 4, stream);

    int gP = (E + PB - 1) / PB;         // 391 partition blocks

    bhist_wtrans<<<gP + 96, 256, 0, stream>>>(dst, bcnt, E, NB, gP, W1, W2, W1t, W2t);
    bscan<<<1, 512, 0, stream>>>(bcnt, bbase, bcur, NB, E);
    part1<<<gP, 256, 0, stream>>>(src, dst, bbase, bcur, pairBuf, E, NB);
    bucket_build<<<NB, 256, 0, stream>>>(pairBuf, bbase, rowptr, deg, dinv, csr, N);

    gemm_mfma<128, true><<<(N + 63) / 64, 256, 0, stream>>>(x, W1t, dinv, H1, N);
    agg_relu_128<<<(N + 15) / 16, 256, 0, stream>>>(H1, csr, rowptr, deg, dinv, b1, A1b, N);
    gemm_mfma<64, false><<<(N + 63) / 64, 256, 0, stream>>>(A1b, W2t, dinv, H2, N);
    agg_lsm_64<<<(N + 15) / 16, 256, 0, stream>>>(H2, csr, rowptr, deg, dinv, b2, out, N);
}

// Round 4
// 255.747 us; speedup vs baseline: 1.0648x; 1.0648x over previous
//
#include <hip/hip_runtime.h>
#include <cstdint>
#include <cstddef>

#define IN_CH 128
#define HID_CH 128
#define OUT_CH 64
#define BSH 8        // nodes per bucket = 256
#define PB 4096      // edges per histogram/partition block

typedef unsigned int uint32;
typedef unsigned char uchar;
typedef short bf16x8 __attribute__((ext_vector_type(8)));
typedef float f32x4 __attribute__((ext_vector_type(4)));
typedef float f32x2 __attribute__((ext_vector_type(2)));

// float -> bf16 round-to-nearest-even
static __device__ __forceinline__ unsigned short f2bf(float f) {
    uint32 u = __float_as_uint(f);
    u += 0x7fffu + ((u >> 16) & 1u);
    return (unsigned short)(u >> 16);
}
// float -> fp8 e4m3 (OCP) single byte via HW cvt
static __device__ __forceinline__ uchar f2fp8(float f) {
    int p = __builtin_amdgcn_cvt_pk_fp8_f32(f, f, 0, false);
    return (uchar)(p & 0xff);
}

// async global->LDS, 16B per lane, register-free (compiler cannot serialize)
typedef const __attribute__((address_space(1))) char gch;
typedef __attribute__((address_space(3))) char lch;
static __device__ __forceinline__ void gload16(const void* g, void* l) {
    __builtin_amdgcn_global_load_lds((gch*)g, (lch*)l, 16, 0, 0);
}

// ---------------- CSR build (bucketed, LDS-atomic only) ----------------

// bhist over buckets; wtrans fused into trailing blocks (independent work).
__global__ __launch_bounds__(256) void bhist_wtrans(
    const int* __restrict__ dst, int* __restrict__ bcnt, int E, int NB, int gP,
    const float* __restrict__ W1, const float* __restrict__ W2,
    unsigned short* __restrict__ W1t, unsigned short* __restrict__ W2t) {
    if (blockIdx.x >= (uint32)gP) {
        int t = (blockIdx.x - gP) * 256 + threadIdx.x;
        if (t < 128 * 128) {
            int nc = t >> 7, k = t & 127;
            W1t[t] = f2bf(W1[k * 128 + nc]);
        }
        int u = t - 128 * 128;
        if (u >= 0 && u < 64 * 128) {
            int nc = u >> 7, k = u & 127;
            W2t[u] = f2bf(W2[k * 64 + nc]);
        }
        return;
    }
    __shared__ int h[512];
    int t = threadIdx.x;
    int e0 = blockIdx.x * PB;
    int cnt = min(PB, E - e0);
    for (int b = t; b < NB; b += 256) h[b] = 0;
    __syncthreads();
    for (int i = t; i < cnt; i += 256)
        atomicAdd(&h[dst[e0 + i] >> BSH], 1);
    __syncthreads();
    for (int b = t; b < NB; b += 256)
        if (h[b]) atomicAdd(&bcnt[b], h[b]);
}

// cursors start at ZERO (part1 adds bbase[b] itself).
__global__ void bscan(const int* __restrict__ bcnt, int* __restrict__ bbase,
                      int* __restrict__ bcur, int NB, int E) {
    __shared__ int s[512];
    int t = threadIdx.x;
    int v = (t < NB) ? bcnt[t] : 0;
    s[t] = v;
    __syncthreads();
    for (int o = 1; o < 512; o <<= 1) {
        int add = (t >= o) ? s[t - o] : 0;
        __syncthreads();
        s[t] += add;
        __syncthreads();
    }
    if (t < NB) { bbase[t] = s[t] - v; bcur[t] = 0; }
    if (t == 0) bbase[NB] = E;
}

// part1: edges cached in LDS (single global read), histogram, then grouped write.
__global__ __launch_bounds__(256) void part1(
    const int* __restrict__ src, const int* __restrict__ dst,
    const int* __restrict__ bbase, int* __restrict__ bcur,
    int2* __restrict__ pairBuf, int E, int NB) {
    __shared__ int2 pairs[PB];          // 32 KB
    __shared__ int hist[512];
    __shared__ int base[512];
    int t = threadIdx.x;
    int e0 = blockIdx.x * PB;
    int cnt = min(PB, E - e0);
    for (int b = t; b < NB; b += 256) hist[b] = 0;
    __syncthreads();
    for (int i = t; i < cnt; i += 256) {
        int s = src[e0 + i], d = dst[e0 + i];
        pairs[i] = make_int2(s, d);
        atomicAdd(&hist[d >> BSH], 1);
    }
    __syncthreads();
    for (int b = t; b < NB; b += 256) {
        int h = hist[b];
        int gb = (h > 0) ? atomicAdd(&bcur[b], h) : 0;
        base[b] = bbase[b] + gb;
        hist[b] = 0;
    }
    __syncthreads();
    for (int i = t; i < cnt; i += 256) {
        int2 p = pairs[i];
        int b = p.y >> BSH;
        int q = base[b] + atomicAdd(&hist[b], 1);
        pairBuf[q] = p;
    }
}

__global__ __launch_bounds__(256) void bucket_build(
    const int2* __restrict__ pairBuf, const int* __restrict__ bbase,
    int* __restrict__ rowptr, int* __restrict__ deg, float* __restrict__ dinv,
    int* __restrict__ csr, int N) {
    __shared__ int cnt[256];
    __shared__ int loc[256];
    int b = blockIdx.x, t = threadIdx.x;
    int start = bbase[b], end = bbase[b + 1];
    cnt[t] = 0;
    __syncthreads();
    for (int i = start + t; i < end; i += 256)
        atomicAdd(&cnt[pairBuf[i].y & 255], 1);
    __syncthreads();
    int v = cnt[t];
    loc[t] = v;
    __syncthreads();
    for (int o = 1; o < 256; o <<= 1) {
        int add = (t >= o) ? loc[t - o] : 0;
        __syncthreads();
        loc[t] += add;
        __syncthreads();
    }
    int excl = loc[t] - v;
    int node = (b << BSH) + t;
    if (node < N) {
        rowptr[node] = start + excl;
        deg[node] = v;
        dinv[node] = rsqrtf((float)(v + 2));   // +2 self-loops
    }
    __syncthreads();
    cnt[t] = excl;                              // reuse as cursor
    __syncthreads();
    for (int i = start + t; i < end; i += 256) {
        int2 p = pairBuf[i];
        int q = start + atomicAdd(&cnt[p.y & 255], 1);
        csr[q] = p.x;
    }
}

// ---------------- MFMA GEMM: C[n,OUT] = dinv[n] * (A[n,128] @ W[128,OUT]) -> fp8 ----
// m97-style staging: A tile (64 rows) via global_load_lds width=16 (register-free,
// fire-and-forget -> the register allocator cannot serialize the stream), W staged
// once into padded LDS (pitch 136 halfwords, conflict-free b128 reads). Persistent
// grid-strided blocks (2-4 blocks/CU co-resident) so one block's MFMA covers the
// other's barrier drain. Single __syncthreads per tile.

template <int OUT, bool AFP32>
__global__ __launch_bounds__(256) void gemm_mfma(
    const void* __restrict__ Av, const unsigned short* __restrict__ Wt,
    const float* __restrict__ dinv, uchar* __restrict__ C, int n, int nTiles) {
    constexpr int NT = OUT / 16;
    constexpr int ROWB = AFP32 ? 512 : 256;        // bytes per A row
    constexpr int TILEB = 64 * ROWB;               // A tile bytes (32K / 16K)
    constexpr int RNDS = TILEB / 4096;             // staging rounds (8 / 4)
    __shared__ unsigned short Ws[OUT * 136];       // padded W (34.8K / 17.4K)
    __shared__ char As[TILEB];                     // linear A tile

    const int t = threadIdx.x;

    // stage W once (padded pitch kills ds_read bank conflicts)
    for (int i = t; i < OUT * 16; i += 256) {
        int rr = i >> 4, sq = i & 15;
        *(uint4*)&Ws[rr * 136 + sq * 8] = *(const uint4*)(Wt + rr * 128 + sq * 8);
    }

    const int w = t >> 6, l = t & 63;
    const int q = l >> 4, r16 = l & 15;
    const int rw = w * 16 + r16;                   // this lane's A row in tile
    const char* Ab = (const char*)Av;

    for (int tile = blockIdx.x; tile < nTiles; tile += gridDim.x) {
        const int row0 = tile * 64;

        // ---- stage A tile: linear LDS dest, per-lane clamped global source ----
#pragma unroll
        for (int rnd = 0; rnd < RNDS; rnd++) {
            int p = rnd * 4096 + t * 16;           // byte position in tile
            int row = row0 + (AFP32 ? (p >> 9) : (p >> 8));
            int col = AFP32 ? (p & 511) : (p & 255);
            gload16(Ab + (size_t)min(row, n - 1) * ROWB + col, As + p);
        }
        __syncthreads();   // drains vmcnt -> tile resident (and W on first iter)

        f32x4 acc[NT];
#pragma unroll
        for (int i = 0; i < NT; i++) acc[i] = (f32x4){0.f, 0.f, 0.f, 0.f};

#pragma unroll
        for (int s = 0; s < 4; s++) {
            const int k0 = s * 32 + q * 8;         // halfword k-offset
            bf16x8 a;
            if (AFP32) {
                const float* Arow = (const float*)(As + rw * 512);
                float4 v0 = *(const float4*)(Arow + k0);
                float4 v1 = *(const float4*)(Arow + k0 + 4);
                a[0] = (short)f2bf(v0.x); a[1] = (short)f2bf(v0.y);
                a[2] = (short)f2bf(v0.z); a[3] = (short)f2bf(v0.w);
                a[4] = (short)f2bf(v1.x); a[5] = (short)f2bf(v1.y);
                a[6] = (short)f2bf(v1.z); a[7] = (short)f2bf(v1.w);
            } else {
                a = *(const bf16x8*)(As + rw * 256 + k0 * 2);
            }
#pragma unroll
            for (int nt = 0; nt < NT; nt++) {
                bf16x8 b = *(const bf16x8*)&Ws[(nt * 16 + r16) * 136 + k0];
                acc[nt] = __builtin_amdgcn_mfma_f32_16x16x32_bf16(a, b, acc[nt], 0, 0, 0);
            }
        }

        // ---- epilogue: dinv pre-scale + fp8 store ----
        const int rbase = row0 + w * 16 + q * 4;
        float4 dv4 = *(const float4*)(dinv + rbase);   // next ws buffer pads OOB tail
        float dva[4] = {dv4.x, dv4.y, dv4.z, dv4.w};
#pragma unroll
        for (int nt = 0; nt < NT; nt++) {
#pragma unroll
            for (int p = 0; p < 4; p++) {
                int rr = rbase + p;
                if (rr < n) C[(size_t)rr * OUT + nt * 16 + r16] = f2fp8(acc[nt][p] * dva[p]);
            }
        }
        __syncthreads();   // protect As from next tile's staging
    }
}

// ---------------- Aggregation: QUARTER-WAVE per node, UNWEIGHTED fp8 sum --------
// H rows arrive pre-scaled by dinv[src] (GEMM epilogue), so the edge loop is a
// pure gather+sum: no per-edge weight gathers/shuffles, f32x2 packed adds
// (v_pk_add_f32), 8 loads in flight per wave iteration.

// agg1: 128 ch, lane covers 8 ch (uint2 = 8 fp8). out = bf16.
__global__ __launch_bounds__(256) void agg_relu_128(
    const uchar* __restrict__ H, const int* __restrict__ csr,
    const int* __restrict__ rowptr, const int* __restrict__ deg,
    const float* __restrict__ dinv, const float* __restrict__ bias,
    unsigned short* __restrict__ out, int n) {
    int v = blockIdx.x * 16 + (threadIdx.x >> 4);
    int hl = threadIdx.x & 15;
    int gsel = threadIdx.x & 48;
    bool valid = v < n;
    int vc = valid ? v : 0;
    int base = rowptr[vc];
    int cnt = valid ? deg[vc] : 0;
    const uint32 co = (uint32)(hl * 8);

    f32x2 A0 = (f32x2){0.f, 0.f}, A1 = A0, A2 = A0, A3 = A0;
    f32x2 B0 = A0, B1 = A0, B2 = A0, B3 = A0;

#define ACC128(h, s0, s1, s2, s3)                                   \
    {                                                               \
        s0 += __builtin_amdgcn_cvt_pk_f32_fp8((h).x, false);        \
        s1 += __builtin_amdgcn_cvt_pk_f32_fp8((h).x, true);         \
        s2 += __builtin_amdgcn_cvt_pk_f32_fp8((h).y, false);        \
        s3 += __builtin_amdgcn_cvt_pk_f32_fp8((h).y, true);         \
    }

    for (int j0 = 0; j0 < cnt; j0 += 16) {
        int nj = min(16, cnt - j0);
        int ul = 0;
        if (hl < nj) ul = csr[base + j0 + hl];
        int j = 0;
        for (; j + 8 <= nj; j += 8) {
            int u0 = __shfl(ul, (j + 0) | gsel), u1 = __shfl(ul, (j + 1) | gsel);
            int u2 = __shfl(ul, (j + 2) | gsel), u3 = __shfl(ul, (j + 3) | gsel);
            int u4 = __shfl(ul, (j + 4) | gsel), u5 = __shfl(ul, (j + 5) | gsel);
            int u6 = __shfl(ul, (j + 6) | gsel), u7 = __shfl(ul, (j + 7) | gsel);
            uint2 h0 = *(const uint2*)(H + (((uint32)u0 << 7) + co));
            uint2 h1 = *(const uint2*)(H + (((uint32)u1 << 7) + co));
            uint2 h2 = *(const uint2*)(H + (((uint32)u2 << 7) + co));
            uint2 h3 = *(const uint2*)(H + (((uint32)u3 << 7) + co));
            uint2 h4 = *(const uint2*)(H + (((uint32)u4 << 7) + co));
            uint2 h5 = *(const uint2*)(H + (((uint32)u5 << 7) + co));
            uint2 h6 = *(const uint2*)(H + (((uint32)u6 << 7) + co));
            uint2 h7 = *(const uint2*)(H + (((uint32)u7 << 7) + co));
            ACC128(h0, A0, A1, A2, A3);
            ACC128(h1, B0, B1, B2, B3);
            ACC128(h2, A0, A1, A2, A3);
            ACC128(h3, B0, B1, B2, B3);
            ACC128(h4, A0, A1, A2, A3);
            ACC128(h5, B0, B1, B2, B3);
            ACC128(h6, A0, A1, A2, A3);
            ACC128(h7, B0, B1, B2, B3);
        }
        for (; j + 4 <= nj; j += 4) {
            int u0 = __shfl(ul, (j + 0) | gsel), u1 = __shfl(ul, (j + 1) | gsel);
            int u2 = __shfl(ul, (j + 2) | gsel), u3 = __shfl(ul, (j + 3) | gsel);
            uint2 h0 = *(const uint2*)(H + (((uint32)u0 << 7) + co));
            uint2 h1 = *(const uint2*)(H + (((uint32)u1 << 7) + co));
            uint2 h2 = *(const uint2*)(H + (((uint32)u2 << 7) + co));
            uint2 h3 = *(const uint2*)(H + (((uint32)u3 << 7) + co));
            ACC128(h0, A0, A1, A2, A3);
            ACC128(h1, B0, B1, B2, B3);
            ACC128(h2, A0, A1, A2, A3);
            ACC128(h3, B0, B1, B2, B3);
        }
        for (; j < nj; j++) {
            int u = __shfl(ul, j | gsel);
            uint2 h = *(const uint2*)(H + (((uint32)u << 7) + co));
            ACC128(h, A0, A1, A2, A3);
        }
    }
#undef ACC128

    if (valid) {
        float dv = dinv[vc];
        uint2 hv = *(const uint2*)(H + (((uint32)vc << 7) + co));
        f32x2 s0 = __builtin_amdgcn_cvt_pk_f32_fp8(hv.x, false);
        f32x2 s1 = __builtin_amdgcn_cvt_pk_f32_fp8(hv.x, true);
        f32x2 s2 = __builtin_amdgcn_cvt_pk_f32_fp8(hv.y, false);
        f32x2 s3 = __builtin_amdgcn_cvt_pk_f32_fp8(hv.y, true);
        const f32x2* bp = (const f32x2*)(bias + hl * 8);
        f32x2 e0 = dv * ((A0 + B0) + 2.f * s0) + bp[0];
        f32x2 e1 = dv * ((A1 + B1) + 2.f * s1) + bp[1];
        f32x2 e2 = dv * ((A2 + B2) + 2.f * s2) + bp[2];
        f32x2 e3 = dv * ((A3 + B3) + 2.f * s3) + bp[3];
        float o0 = fmaxf(e0[0], 0.f), o1 = fmaxf(e0[1], 0.f);
        float o2 = fmaxf(e1[0], 0.f), o3 = fmaxf(e1[1], 0.f);
        float o4 = fmaxf(e2[0], 0.f), o5 = fmaxf(e2[1], 0.f);
        float o6 = fmaxf(e3[0], 0.f), o7 = fmaxf(e3[1], 0.f);
        uint4 pk;
        pk.x = (uint32)f2bf(o0) | ((uint32)f2bf(o1) << 16);
        pk.y = (uint32)f2bf(o2) | ((uint32)f2bf(o3) << 16);
        pk.z = (uint32)f2bf(o4) | ((uint32)f2bf(o5) << 16);
        pk.w = (uint32)f2bf(o6) | ((uint32)f2bf(o7) << 16);
        *(uint4*)(out + (size_t)vc * 128 + hl * 8) = pk;
    }
}

// agg2: 64 ch, lane covers 4 ch (uint = 4 fp8). log_softmax within group of 16.
__global__ __launch_bounds__(256) void agg_lsm_64(
    const uchar* __restrict__ H, const int* __restrict__ csr,
    const int* __restrict__ rowptr, const int* __restrict__ deg,
    const float* __restrict__ dinv, const float* __restrict__ bias,
    float* __restrict__ out, int n) {
    int v = blockIdx.x * 16 + (threadIdx.x >> 4);
    int hl = threadIdx.x & 15;
    int gsel = threadIdx.x & 48;
    bool valid = v < n;
    int vc = valid ? v : 0;
    int base = rowptr[vc];
    int cnt = valid ? deg[vc] : 0;
    const uint32 co = (uint32)(hl * 4);

    f32x2 A0 = (f32x2){0.f, 0.f}, A1 = A0, B0 = A0, B1 = A0;

#define ACC64(h, s0, s1)                                            \
    {                                                               \
        s0 += __builtin_amdgcn_cvt_pk_f32_fp8((h), false);          \
        s1 += __builtin_amdgcn_cvt_pk_f32_fp8((h), true);           \
    }

    for (int j0 = 0; j0 < cnt; j0 += 16) {
        int nj = min(16, cnt - j0);
        int ul = 0;
        if (hl < nj) ul = csr[base + j0 + hl];
        int j = 0;
        for (; j + 8 <= nj; j += 8) {
            int u0 = __shfl(ul, (j + 0) | gsel), u1 = __shfl(ul, (j + 1) | gsel);
            int u2 = __shfl(ul, (j + 2) | gsel), u3 = __shfl(ul, (j + 3) | gsel);
            int u4 = __shfl(ul, (j + 4) | gsel), u5 = __shfl(ul, (j + 5) | gsel);
            int u6 = __shfl(ul, (j + 6) | gsel), u7 = __shfl(ul, (j + 7) | gsel);
            uint32 h0 = *(const uint32*)(H + (((uint32)u0 << 6) + co));
            uint32 h1 = *(const uint32*)(H + (((uint32)u1 << 6) + co));
            uint32 h2 = *(const uint32*)(H + (((uint32)u2 << 6) + co));
            uint32 h3 = *(const uint32*)(H + (((uint32)u3 << 6) + co));
            uint32 h4 = *(const uint32*)(H + (((uint32)u4 << 6) + co));
            uint32 h5 = *(const uint32*)(H + (((uint32)u5 << 6) + co));
            uint32 h6 = *(const uint32*)(H + (((uint32)u6 << 6) + co));
            uint32 h7 = *(const uint32*)(H + (((uint32)u7 << 6) + co));
            ACC64(h0, A0, A1);
            ACC64(h1, B0, B1);
            ACC64(h2, A0, A1);
            ACC64(h3, B0, B1);
            ACC64(h4, A0, A1);
            ACC64(h5, B0, B1);
            ACC64(h6, A0, A1);
            ACC64(h7, B0, B1);
        }
        for (; j + 4 <= nj; j += 4) {
            int u0 = __shfl(ul, (j + 0) | gsel), u1 = __shfl(ul, (j + 1) | gsel);
            int u2 = __shfl(ul, (j + 2) | gsel), u3 = __shfl(ul, (j + 3) | gsel);
            uint32 h0 = *(const uint32*)(H + (((uint32)u0 << 6) + co));
            uint32 h1 = *(const uint32*)(H + (((uint32)u1 << 6) + co));
            uint32 h2 = *(const uint32*)(H + (((uint32)u2 << 6) + co));
            uint32 h3 = *(const uint32*)(H + (((uint32)u3 << 6) + co));
            ACC64(h0, A0, A1);
            ACC64(h1, B0, B1);
            ACC64(h2, A0, A1);
            ACC64(h3, B0, B1);
        }
        for (; j < nj; j++) {
            int u = __shfl(ul, j | gsel);
            uint32 h = *(const uint32*)(H + (((uint32)u << 6) + co));
            ACC64(h, A0, A1);
        }
    }
#undef ACC64

    float dv = dinv[vc];
    uint32 hv = *(const uint32*)(H + (((uint32)vc << 6) + co));
    f32x2 s0 = __builtin_amdgcn_cvt_pk_f32_fp8(hv, false);
    f32x2 s1 = __builtin_amdgcn_cvt_pk_f32_fp8(hv, true);
    const f32x2* bp = (const f32x2*)(bias + hl * 4);
    f32x2 w0 = dv * ((A0 + B0) + 2.f * s0) + bp[0];
    f32x2 w1 = dv * ((A1 + B1) + 2.f * s1) + bp[1];
    float v0 = w0[0], v1 = w0[1], v2 = w1[0], v3 = w1[1];
    // log_softmax across the 64 channels held by this 16-lane group
    float m = fmaxf(fmaxf(v0, v1), fmaxf(v2, v3));
    for (int o = 8; o > 0; o >>= 1) m = fmaxf(m, __shfl_xor(m, o));
    float e = (__expf(v0 - m) + __expf(v1 - m)) + (__expf(v2 - m) + __expf(v3 - m));
    for (int o = 8; o > 0; o >>= 1) e += __shfl_xor(e, o);
    float ls = m + __logf(e);
    if (valid)
        *(float4*)(out + (size_t)vc * 64 + hl * 4) =
            make_float4(v0 - ls, v1 - ls, v2 - ls, v3 - ls);
}

// ---------------- launch ----------------

extern "C" void kernel_launch(void* const* d_in, const int* in_sizes, int n_in,
                              void* d_out, int out_size, void* d_ws, size_t ws_size,
                              hipStream_t stream) {
    const float* x  = (const float*)d_in[0];
    const int*   ei = (const int*)d_in[1];
    const float* W1 = (const float*)d_in[2];
    const float* b1 = (const float*)d_in[3];
    const float* W2 = (const float*)d_in[4];
    const float* b2 = (const float*)d_in[5];
    float* out = (float*)d_out;

    const int N = in_sizes[0] / IN_CH;  // 100000
    const int E = in_sizes[1] / 2;      // 1600000
    const int* src = ei;
    const int* dst = ei + E;
    const int NB = (N + 255) >> BSH;    // 391 buckets

    char* w = (char*)d_ws;
    size_t off = 0;
    auto alloc = [&](size_t bytes) -> char* {
        char* p = w + off;
        off = (off + bytes + 255) & ~(size_t)255;
        return p;
    };
    int*   deg    = (int*)alloc((size_t)N * 4);
    int*   rowptr = (int*)alloc((size_t)N * 4);
    int*   bcnt   = (int*)alloc(512 * 4);
    int*   bbase  = (int*)alloc(513 * 4);
    int*   bcur   = (int*)alloc(512 * 4);
    float* dinv   = (float*)alloc((size_t)N * 4 + 1024);  // +pad: gemm epilogue float4 tail
    int*   csr    = (int*)alloc((size_t)E * 4);
    unsigned short* W1t = (unsigned short*)alloc(128 * 128 * 2);
    unsigned short* W2t = (unsigned short*)alloc(64 * 128 * 2);
    uchar* H1  = (uchar*)alloc((size_t)N * HID_CH);          // fp8, 12.8 MB
    unsigned short* A1b = (unsigned short*)alloc((size_t)N * HID_CH * 2);  // bf16
    uchar* H2  = H1;                     // fp8; H1 dead after agg1
    int2*  pairBuf = (int2*)A1b;         // A1b not written until agg1 (after bucket_build)

    hipMemsetAsync(bcnt, 0, 512 * 4, stream);

    int gP = (E + PB - 1) / PB;         // 391 partition blocks

    bhist_wtrans<<<gP + 96, 256, 0, stream>>>(dst, bcnt, E, NB, gP, W1, W2, W1t, W2t);
    bscan<<<1, 512, 0, stream>>>(bcnt, bbase, bcur, NB, E);
    part1<<<gP, 256, 0, stream>>>(src, dst, bbase, bcur, pairBuf, E, NB);
    bucket_build<<<NB, 256, 0, stream>>>(pairBuf, bbase, rowptr, deg, dinv, csr, N);

    const int nTiles = (N + 63) / 64;   // 1563
    const int gG = min(nTiles, 512);    // persistent grid-stride blocks
    gemm_mfma<128, true><<<gG, 256, 0, stream>>>(x, W1t, dinv, H1, N, nTiles);
    agg_relu_128<<<(N + 15) / 16, 256, 0, stream>>>(H1, csr, rowptr, deg, dinv, b1, A1b, N);
    gemm_mfma<64, false><<<gG, 256, 0, stream>>>(A1b, W2t, dinv, H2, N, nTiles);
    agg_lsm_64<<<(N + 15) / 16, 256, 0, stream>>>(H2, csr, rowptr, deg, dinv, b2, out, N);
}

// Round 5
// 242.385 us; speedup vs baseline: 1.1235x; 1.0551x over previous
//
#include <hip/hip_runtime.h>
#include <cstdint>
#include <cstddef>

#define IN_CH 128
#define HID_CH 128
#define OUT_CH 64
#define BSH 8        // nodes per bucket = 256
#define PB 4096      // edges per histogram/partition block

typedef unsigned int uint32;
typedef unsigned char uchar;
typedef short bf16x8 __attribute__((ext_vector_type(8)));
typedef float f32x4 __attribute__((ext_vector_type(4)));
typedef float f32x2 __attribute__((ext_vector_type(2)));

// float -> bf16 round-to-nearest-even
static __device__ __forceinline__ unsigned short f2bf(float f) {
    uint32 u = __float_as_uint(f);
    u += 0x7fffu + ((u >> 16) & 1u);
    return (unsigned short)(u >> 16);
}

// async global->LDS, 16B per lane, register-free (compiler cannot serialize)
typedef const __attribute__((address_space(1))) char gch;
typedef __attribute__((address_space(3))) char lch;
static __device__ __forceinline__ void gload16(const void* g, void* l) {
    __builtin_amdgcn_global_load_lds((gch*)g, (lch*)l, 16, 0, 0);
}

// ---------------- CSR build (bucketed, LDS-atomic only) ----------------

// bhist over buckets; wtrans fused into trailing blocks (independent work).
__global__ __launch_bounds__(256) void bhist_wtrans(
    const int* __restrict__ dst, int* __restrict__ bcnt, int E, int NB, int gP,
    const float* __restrict__ W1, const float* __restrict__ W2,
    unsigned short* __restrict__ W1t, unsigned short* __restrict__ W2t) {
    if (blockIdx.x >= (uint32)gP) {
        int t = (blockIdx.x - gP) * 256 + threadIdx.x;
        if (t < 128 * 128) {
            int nc = t >> 7, k = t & 127;
            W1t[t] = f2bf(W1[k * 128 + nc]);
        }
        int u = t - 128 * 128;
        if (u >= 0 && u < 64 * 128) {
            int nc = u >> 7, k = u & 127;
            W2t[u] = f2bf(W2[k * 64 + nc]);
        }
        return;
    }
    __shared__ int h[512];
    int t = threadIdx.x;
    int e0 = blockIdx.x * PB;
    int cnt = min(PB, E - e0);
    for (int b = t; b < NB; b += 256) h[b] = 0;
    __syncthreads();
    for (int i = t; i < cnt; i += 256)
        atomicAdd(&h[dst[e0 + i] >> BSH], 1);
    __syncthreads();
    for (int b = t; b < NB; b += 256)
        if (h[b]) atomicAdd(&bcnt[b], h[b]);
}

// cursors start at ZERO (part1 adds bbase[b] itself).
__global__ void bscan(const int* __restrict__ bcnt, int* __restrict__ bbase,
                      int* __restrict__ bcur, int NB, int E) {
    __shared__ int s[512];
    int t = threadIdx.x;
    int v = (t < NB) ? bcnt[t] : 0;
    s[t] = v;
    __syncthreads();
    for (int o = 1; o < 512; o <<= 1) {
        int add = (t >= o) ? s[t - o] : 0;
        __syncthreads();
        s[t] += add;
        __syncthreads();
    }
    if (t < NB) { bbase[t] = s[t] - v; bcur[t] = 0; }
    if (t == 0) bbase[NB] = E;
}

// part1: edges cached in LDS (single global read), histogram, then grouped write.
__global__ __launch_bounds__(256) void part1(
    const int* __restrict__ src, const int* __restrict__ dst,
    const int* __restrict__ bbase, int* __restrict__ bcur,
    int2* __restrict__ pairBuf, int E, int NB) {
    __shared__ int2 pairs[PB];          // 32 KB
    __shared__ int hist[512];
    __shared__ int base[512];
    int t = threadIdx.x;
    int e0 = blockIdx.x * PB;
    int cnt = min(PB, E - e0);
    for (int b = t; b < NB; b += 256) hist[b] = 0;
    __syncthreads();
    for (int i = t; i < cnt; i += 256) {
        int s = src[e0 + i], d = dst[e0 + i];
        pairs[i] = make_int2(s, d);
        atomicAdd(&hist[d >> BSH], 1);
    }
    __syncthreads();
    for (int b = t; b < NB; b += 256) {
        int h = hist[b];
        int gb = (h > 0) ? atomicAdd(&bcur[b], h) : 0;
        base[b] = bbase[b] + gb;
        hist[b] = 0;
    }
    __syncthreads();
    for (int i = t; i < cnt; i += 256) {
        int2 p = pairs[i];
        int b = p.y >> BSH;
        int q = base[b] + atomicAdd(&hist[b], 1);
        pairBuf[q] = p;
    }
}

__global__ __launch_bounds__(256) void bucket_build(
    const int2* __restrict__ pairBuf, const int* __restrict__ bbase,
    int* __restrict__ rowptr, int* __restrict__ deg, float* __restrict__ dinv,
    int* __restrict__ csr, int N) {
    __shared__ int cnt[256];
    __shared__ int loc[256];
    int b = blockIdx.x, t = threadIdx.x;
    int start = bbase[b], end = bbase[b + 1];
    cnt[t] = 0;
    __syncthreads();
    for (int i = start + t; i < end; i += 256)
        atomicAdd(&cnt[pairBuf[i].y & 255], 1);
    __syncthreads();
    int v = cnt[t];
    loc[t] = v;
    __syncthreads();
    for (int o = 1; o < 256; o <<= 1) {
        int add = (t >= o) ? loc[t - o] : 0;
        __syncthreads();
        loc[t] += add;
        __syncthreads();
    }
    int excl = loc[t] - v;
    int node = (b << BSH) + t;
    if (node < N) {
        rowptr[node] = start + excl;
        deg[node] = v;
        dinv[node] = rsqrtf((float)(v + 2));   // +2 self-loops
    }
    __syncthreads();
    cnt[t] = excl;                              // reuse as cursor
    __syncthreads();
    for (int i = start + t; i < end; i += 256) {
        int2 p = pairBuf[i];
        int q = start + atomicAdd(&cnt[p.y & 255], 1);
        csr[q] = p.x;
    }
}

// ---------------- MFMA GEMM1: H1[n,128] = fp8(dinv[n] * (x[n,128] @ W1)) ----------
// m97-style staging (global_load_lds width=16, register-free) + OPERAND-SWAPPED
// MFMA: pass (W-frag, x-frag) so each lane's acc[nt][p] holds 4 CONSECUTIVE
// channels of ONE node -> epilogue is one scalar dinv, 2x cvt_pk_fp8 and a single
// dword store per nt (8 dword stores vs 32 scattered byte stores).

__global__ __launch_bounds__(256) void gemm1_mfma(
    const float* __restrict__ A, const unsigned short* __restrict__ Wt,
    const float* __restrict__ dinv, uchar* __restrict__ C, int n, int nTiles) {
    constexpr int NT = 8;                          // 128 out channels / 16
    __shared__ unsigned short Ws[128 * 136];       // padded W (34.8K)
    __shared__ char As[64 * 512];                  // 64-row fp32 tile (32K)

    const int t = threadIdx.x;

    // stage W once (padded pitch kills ds_read bank conflicts)
    for (int i = t; i < 128 * 16; i += 256) {
        int rr = i >> 4, sq = i & 15;
        *(uint4*)&Ws[rr * 136 + sq * 8] = *(const uint4*)(Wt + rr * 128 + sq * 8);
    }

    const int w = t >> 6, l = t & 63;
    const int q = l >> 4, r16 = l & 15;
    const int rw = w * 16 + r16;                   // this lane's node row in tile

    for (int tile = blockIdx.x; tile < nTiles; tile += gridDim.x) {
        const int row0 = tile * 64;

        // ---- stage A tile: linear LDS dest, per-lane clamped global source ----
#pragma unroll
        for (int rnd = 0; rnd < 8; rnd++) {
            int p = rnd * 4096 + t * 16;           // byte position in tile
            int row = row0 + (p >> 9);
            int col = p & 511;
            gload16((const char*)A + (size_t)min(row, n - 1) * 512 + col, As + p);
        }
        __syncthreads();   // drains vmcnt -> tile resident (and W on first iter)

        f32x4 acc[NT];
#pragma unroll
        for (int i = 0; i < NT; i++) acc[i] = (f32x4){0.f, 0.f, 0.f, 0.f};

#pragma unroll
        for (int s = 0; s < 4; s++) {
            const int k0 = s * 32 + q * 8;         // element k-offset
            // x-fragment (B operand: lane&15 -> node col)
            const float* Arow = (const float*)(As + rw * 512);
            float4 v0 = *(const float4*)(Arow + k0);
            float4 v1 = *(const float4*)(Arow + k0 + 4);
            bf16x8 xf;
            xf[0] = (short)f2bf(v0.x); xf[1] = (short)f2bf(v0.y);
            xf[2] = (short)f2bf(v0.z); xf[3] = (short)f2bf(v0.w);
            xf[4] = (short)f2bf(v1.x); xf[5] = (short)f2bf(v1.y);
            xf[6] = (short)f2bf(v1.z); xf[7] = (short)f2bf(v1.w);
#pragma unroll
            for (int nt = 0; nt < NT; nt++) {
                // W-fragment (A operand: lane&15 -> channel row)
                bf16x8 wf = *(const bf16x8*)&Ws[(nt * 16 + r16) * 136 + k0];
                acc[nt] = __builtin_amdgcn_mfma_f32_16x16x32_bf16(wf, xf, acc[nt], 0, 0, 0);
            }
        }

        // ---- epilogue: acc[nt][p] = channel (nt*16 + q*4 + p) of node rw ----
        const int node = row0 + rw;
        const bool nv = node < n;
        const float dv = dinv[min(node, n - 1)];
        uchar* Crow = C + (size_t)node * 128;
#pragma unroll
        for (int nt = 0; nt < NT; nt++) {
            int pk = 0;
            pk = __builtin_amdgcn_cvt_pk_fp8_f32(acc[nt][0] * dv, acc[nt][1] * dv, pk, false);
            pk = __builtin_amdgcn_cvt_pk_fp8_f32(acc[nt][2] * dv, acc[nt][3] * dv, pk, true);
            if (nv) *(uint32*)(Crow + nt * 16 + q * 4) = (uint32)pk;
        }
        __syncthreads();   // protect As from next tile's staging
    }
}

// ---------------- Fused agg1 + gemm2 -------------------------------------------
// Phase 1: quarter-wave-per-node UNWEIGHTED fp8 gather-sum of H1 (pre-scaled by
//   dinv[src] in gemm1), + self-loop + bias + ReLU -> 128-ch hidden (bf16).
// Phase 2: stage the block's 16x128 bf16 hidden tile in LDS, one barrier.
// Phase 3: per-wave MFMA (operand-swapped) computes hid @ W2 for 16 channels x
//   16 nodes; epilogue scales by dinv[node] and stores fp8 H2 dwords.
// This deletes the standalone gemm2 dispatch + 51 MB of A1b traffic.

__global__ __launch_bounds__(256) void agg1_fused(
    const uchar* __restrict__ H, const int* __restrict__ csr,
    const int* __restrict__ rowptr, const int* __restrict__ deg,
    const float* __restrict__ dinv, const float* __restrict__ bias,
    const unsigned short* __restrict__ W2t, uchar* __restrict__ H2, int n) {
    __shared__ unsigned short tile[16 * 136];      // 16 nodes x 128ch bf16, padded
    int t = threadIdx.x;
    int g = t >> 4;                                 // node slot in block (0..15)
    int v = blockIdx.x * 16 + g;
    int hl = t & 15;
    int gsel = t & 48;
    bool valid = v < n;
    int vc = valid ? v : 0;
    int base = rowptr[vc];
    int cnt = valid ? deg[vc] : 0;
    const uint32 co = (uint32)(hl * 8);

    f32x2 A0 = (f32x2){0.f, 0.f}, A1 = A0, A2 = A0, A3 = A0;
    f32x2 B0 = A0, B1 = A0, B2 = A0, B3 = A0;

#define ACC128(h, s0, s1, s2, s3)                                   \
    {                                                               \
        s0 += __builtin_amdgcn_cvt_pk_f32_fp8((h).x, false);        \
        s1 += __builtin_amdgcn_cvt_pk_f32_fp8((h).x, true);         \
        s2 += __builtin_amdgcn_cvt_pk_f32_fp8((h).y, false);        \
        s3 += __builtin_amdgcn_cvt_pk_f32_fp8((h).y, true);         \
    }

    for (int j0 = 0; j0 < cnt; j0 += 16) {
        int nj = min(16, cnt - j0);
        int ul = 0;
        if (hl < nj) ul = csr[base + j0 + hl];
        int j = 0;
        for (; j + 8 <= nj; j += 8) {
            int u0 = __shfl(ul, (j + 0) | gsel), u1 = __shfl(ul, (j + 1) | gsel);
            int u2 = __shfl(ul, (j + 2) | gsel), u3 = __shfl(ul, (j + 3) | gsel);
            int u4 = __shfl(ul, (j + 4) | gsel), u5 = __shfl(ul, (j + 5) | gsel);
            int u6 = __shfl(ul, (j + 6) | gsel), u7 = __shfl(ul, (j + 7) | gsel);
            uint2 h0 = *(const uint2*)(H + (((uint32)u0 << 7) + co));
            uint2 h1 = *(const uint2*)(H + (((uint32)u1 << 7) + co));
            uint2 h2 = *(const uint2*)(H + (((uint32)u2 << 7) + co));
            uint2 h3 = *(const uint2*)(H + (((uint32)u3 << 7) + co));
            uint2 h4 = *(const uint2*)(H + (((uint32)u4 << 7) + co));
            uint2 h5 = *(const uint2*)(H + (((uint32)u5 << 7) + co));
            uint2 h6 = *(const uint2*)(H + (((uint32)u6 << 7) + co));
            uint2 h7 = *(const uint2*)(H + (((uint32)u7 << 7) + co));
            ACC128(h0, A0, A1, A2, A3);
            ACC128(h1, B0, B1, B2, B3);
            ACC128(h2, A0, A1, A2, A3);
            ACC128(h3, B0, B1, B2, B3);
            ACC128(h4, A0, A1, A2, A3);
            ACC128(h5, B0, B1, B2, B3);
            ACC128(h6, A0, A1, A2, A3);
            ACC128(h7, B0, B1, B2, B3);
        }
        for (; j + 4 <= nj; j += 4) {
            int u0 = __shfl(ul, (j + 0) | gsel), u1 = __shfl(ul, (j + 1) | gsel);
            int u2 = __shfl(ul, (j + 2) | gsel), u3 = __shfl(ul, (j + 3) | gsel);
            uint2 h0 = *(const uint2*)(H + (((uint32)u0 << 7) + co));
            uint2 h1 = *(const uint2*)(H + (((uint32)u1 << 7) + co));
            uint2 h2 = *(const uint2*)(H + (((uint32)u2 << 7) + co));
            uint2 h3 = *(const uint2*)(H + (((uint32)u3 << 7) + co));
            ACC128(h0, A0, A1, A2, A3);
            ACC128(h1, B0, B1, B2, B3);
            ACC128(h2, A0, A1, A2, A3);
            ACC128(h3, B0, B1, B2, B3);
        }
        for (; j < nj; j++) {
            int u = __shfl(ul, j | gsel);
            uint2 h = *(const uint2*)(H + (((uint32)u << 7) + co));
            ACC128(h, A0, A1, A2, A3);
        }
    }
#undef ACC128

    // ---- finish hidden: self-loop + bias + ReLU, pack bf16 ----
    uint4 pk = make_uint4(0, 0, 0, 0);
    if (valid) {
        float dv = dinv[vc];
        uint2 hv = *(const uint2*)(H + (((uint32)vc << 7) + co));
        f32x2 s0 = __builtin_amdgcn_cvt_pk_f32_fp8(hv.x, false);
        f32x2 s1 = __builtin_amdgcn_cvt_pk_f32_fp8(hv.x, true);
        f32x2 s2 = __builtin_amdgcn_cvt_pk_f32_fp8(hv.y, false);
        f32x2 s3 = __builtin_amdgcn_cvt_pk_f32_fp8(hv.y, true);
        const f32x2* bp = (const f32x2*)(bias + hl * 8);
        f32x2 e0 = dv * ((A0 + B0) + 2.f * s0) + bp[0];
        f32x2 e1 = dv * ((A1 + B1) + 2.f * s1) + bp[1];
        f32x2 e2 = dv * ((A2 + B2) + 2.f * s2) + bp[2];
        f32x2 e3 = dv * ((A3 + B3) + 2.f * s3) + bp[3];
        float o0 = fmaxf(e0[0], 0.f), o1 = fmaxf(e0[1], 0.f);
        float o2 = fmaxf(e1[0], 0.f), o3 = fmaxf(e1[1], 0.f);
        float o4 = fmaxf(e2[0], 0.f), o5 = fmaxf(e2[1], 0.f);
        float o6 = fmaxf(e3[0], 0.f), o7 = fmaxf(e3[1], 0.f);
        pk.x = (uint32)f2bf(o0) | ((uint32)f2bf(o1) << 16);
        pk.y = (uint32)f2bf(o2) | ((uint32)f2bf(o3) << 16);
        pk.z = (uint32)f2bf(o4) | ((uint32)f2bf(o5) << 16);
        pk.w = (uint32)f2bf(o6) | ((uint32)f2bf(o7) << 16);
    }
    *(uint4*)&tile[g * 136 + hl * 8] = pk;
    __syncthreads();

    // ---- gemm2 tail: wave w -> channels w*16..+15 for all 16 nodes ----
    const int w = t >> 6, l = t & 63;
    const int q = l >> 4, r16 = l & 15;
    f32x4 acc2 = (f32x4){0.f, 0.f, 0.f, 0.f};
#pragma unroll
    for (int s = 0; s < 4; s++) {
        const int k0 = s * 32 + q * 8;
        bf16x8 hf = *(const bf16x8*)&tile[r16 * 136 + k0];                 // node r16
        bf16x8 wf = *(const bf16x8*)(W2t + (size_t)(w * 16 + r16) * 128 + k0); // channel
        acc2 = __builtin_amdgcn_mfma_f32_16x16x32_bf16(wf, hf, acc2, 0, 0, 0);
    }
    const int node = blockIdx.x * 16 + r16;
    if (node < n) {
        const float dv2 = dinv[node];
        int pk2 = 0;
        pk2 = __builtin_amdgcn_cvt_pk_fp8_f32(acc2[0] * dv2, acc2[1] * dv2, pk2, false);
        pk2 = __builtin_amdgcn_cvt_pk_fp8_f32(acc2[2] * dv2, acc2[3] * dv2, pk2, true);
        *(uint32*)(H2 + (size_t)node * 64 + w * 16 + q * 4) = (uint32)pk2;
    }
}

// agg2: 64 ch, lane covers 4 ch (uint = 4 fp8). log_softmax within group of 16.
__global__ __launch_bounds__(256) void agg_lsm_64(
    const uchar* __restrict__ H, const int* __restrict__ csr,
    const int* __restrict__ rowptr, const int* __restrict__ deg,
    const float* __restrict__ dinv, const float* __restrict__ bias,
    float* __restrict__ out, int n) {
    int v = blockIdx.x * 16 + (threadIdx.x >> 4);
    int hl = threadIdx.x & 15;
    int gsel = threadIdx.x & 48;
    bool valid = v < n;
    int vc = valid ? v : 0;
    int base = rowptr[vc];
    int cnt = valid ? deg[vc] : 0;
    const uint32 co = (uint32)(hl * 4);

    f32x2 A0 = (f32x2){0.f, 0.f}, A1 = A0, B0 = A0, B1 = A0;

#define ACC64(h, s0, s1)                                            \
    {                                                               \
        s0 += __builtin_amdgcn_cvt_pk_f32_fp8((h), false);          \
        s1 += __builtin_amdgcn_cvt_pk_f32_fp8((h), true);           \
    }

    for (int j0 = 0; j0 < cnt; j0 += 16) {
        int nj = min(16, cnt - j0);
        int ul = 0;
        if (hl < nj) ul = csr[base + j0 + hl];
        int j = 0;
        for (; j + 8 <= nj; j += 8) {
            int u0 = __shfl(ul, (j + 0) | gsel), u1 = __shfl(ul, (j + 1) | gsel);
            int u2 = __shfl(ul, (j + 2) | gsel), u3 = __shfl(ul, (j + 3) | gsel);
            int u4 = __shfl(ul, (j + 4) | gsel), u5 = __shfl(ul, (j + 5) | gsel);
            int u6 = __shfl(ul, (j + 6) | gsel), u7 = __shfl(ul, (j + 7) | gsel);
            uint32 h0 = *(const uint32*)(H + (((uint32)u0 << 6) + co));
            uint32 h1 = *(const uint32*)(H + (((uint32)u1 << 6) + co));
            uint32 h2 = *(const uint32*)(H + (((uint32)u2 << 6) + co));
            uint32 h3 = *(const uint32*)(H + (((uint32)u3 << 6) + co));
            uint32 h4 = *(const uint32*)(H + (((uint32)u4 << 6) + co));
            uint32 h5 = *(const uint32*)(H + (((uint32)u5 << 6) + co));
            uint32 h6 = *(const uint32*)(H + (((uint32)u6 << 6) + co));
            uint32 h7 = *(const uint32*)(H + (((uint32)u7 << 6) + co));
            ACC64(h0, A0, A1);
            ACC64(h1, B0, B1);
            ACC64(h2, A0, A1);
            ACC64(h3, B0, B1);
            ACC64(h4, A0, A1);
            ACC64(h5, B0, B1);
            ACC64(h6, A0, A1);
            ACC64(h7, B0, B1);
        }
        for (; j + 4 <= nj; j += 4) {
            int u0 = __shfl(ul, (j + 0) | gsel), u1 = __shfl(ul, (j + 1) | gsel);
            int u2 = __shfl(ul, (j + 2) | gsel), u3 = __shfl(ul, (j + 3) | gsel);
            uint32 h0 = *(const uint32*)(H + (((uint32)u0 << 6) + co));
            uint32 h1 = *(const uint32*)(H + (((uint32)u1 << 6) + co));
            uint32 h2 = *(const uint32*)(H + (((uint32)u2 << 6) + co));
            uint32 h3 = *(const uint32*)(H + (((uint32)u3 << 6) + co));
            ACC64(h0, A0, A1);
            ACC64(h1, B0, B1);
            ACC64(h2, A0, A1);
            ACC64(h3, B0, B1);
        }
        for (; j < nj; j++) {
            int u = __shfl(ul, j | gsel);
            uint32 h = *(const uint32*)(H + (((uint32)u << 6) + co));
            ACC64(h, A0, A1);
        }
    }
#undef ACC64

    float dv = dinv[vc];
    uint32 hv = *(const uint32*)(H + (((uint32)vc << 6) + co));
    f32x2 s0 = __builtin_amdgcn_cvt_pk_f32_fp8(hv, false);
    f32x2 s1 = __builtin_amdgcn_cvt_pk_f32_fp8(hv, true);
    const f32x2* bp = (const f32x2*)(bias + hl * 4);
    f32x2 w0 = dv * ((A0 + B0) + 2.f * s0) + bp[0];
    f32x2 w1 = dv * ((A1 + B1) + 2.f * s1) + bp[1];
    float v0 = w0[0], v1 = w0[1], v2 = w1[0], v3 = w1[1];
    // log_softmax across the 64 channels held by this 16-lane group
    float m = fmaxf(fmaxf(v0, v1), fmaxf(v2, v3));
    for (int o = 8; o > 0; o >>= 1) m = fmaxf(m, __shfl_xor(m, o));
    float e = (__expf(v0 - m) + __expf(v1 - m)) + (__expf(v2 - m) + __expf(v3 - m));
    for (int o = 8; o > 0; o >>= 1) e += __shfl_xor(e, o);
    float ls = m + __logf(e);
    if (valid)
        *(float4*)(out + (size_t)vc * 64 + hl * 4) =
            make_float4(v0 - ls, v1 - ls, v2 - ls, v3 - ls);
}

// ---------------- launch ----------------

extern "C" void kernel_launch(void* const* d_in, const int* in_sizes, int n_in,
                              void* d_out, int out_size, void* d_ws, size_t ws_size,
                              hipStream_t stream) {
    const float* x  = (const float*)d_in[0];
    const int*   ei = (const int*)d_in[1];
    const float* W1 = (const float*)d_in[2];
    const float* b1 = (const float*)d_in[3];
    const float* W2 = (const float*)d_in[4];
    const float* b2 = (const float*)d_in[5];
    float* out = (float*)d_out;

    const int N = in_sizes[0] / IN_CH;  // 100000
    const int E = in_sizes[1] / 2;      // 1600000
    const int* src = ei;
    const int* dst = ei + E;
    const int NB = (N + 255) >> BSH;    // 391 buckets

    char* w = (char*)d_ws;
    size_t off = 0;
    auto alloc = [&](size_t bytes) -> char* {
        char* p = w + off;
        off = (off + bytes + 255) & ~(size_t)255;
        return p;
    };
    int*   deg    = (int*)alloc((size_t)N * 4);
    int*   rowptr = (int*)alloc((size_t)N * 4);
    int*   bcnt   = (int*)alloc(512 * 4);
    int*   bbase  = (int*)alloc(513 * 4);
    int*   bcur   = (int*)alloc(512 * 4);
    float* dinv   = (float*)alloc((size_t)N * 4 + 1024);  // +pad for vector tails
    int*   csr    = (int*)alloc((size_t)E * 4);
    unsigned short* W1t = (unsigned short*)alloc(128 * 128 * 2);
    unsigned short* W2t = (unsigned short*)alloc(64 * 128 * 2);
    uchar* H1  = (uchar*)alloc((size_t)N * HID_CH);          // fp8, 12.8 MB
    char*  scratch = alloc((size_t)E * 8);                   // pairBuf then H2
    uchar* H2  = (uchar*)scratch;        // fp8, 6.4 MB (pairBuf dead after bucket_build)
    int2*  pairBuf = (int2*)scratch;

    hipMemsetAsync(bcnt, 0, 512 * 4, stream);

    int gP = (E + PB - 1) / PB;         // 391 partition blocks

    bhist_wtrans<<<gP + 96, 256, 0, stream>>>(dst, bcnt, E, NB, gP, W1, W2, W1t, W2t);
    bscan<<<1, 512, 0, stream>>>(bcnt, bbase, bcur, NB, E);
    part1<<<gP, 256, 0, stream>>>(src, dst, bbase, bcur, pairBuf, E, NB);
    bucket_build<<<NB, 256, 0, stream>>>(pairBuf, bbase, rowptr, deg, dinv, csr, N);

    const int nTiles = (N + 63) / 64;   // 1563
    const int gG = min(nTiles, 512);    // persistent grid-stride blocks
    gemm1_mfma<<<gG, 256, 0, stream>>>(x, W1t, dinv, H1, N, nTiles);
    agg1_fused<<<(N + 15) / 16, 256, 0, stream>>>(H1, csr, rowptr, deg, dinv, b1, W2t, H2, N);
    agg_lsm_64<<<(N + 15) / 16, 256, 0, stream>>>(H2, csr, rowptr, deg, dinv, b2, out, N);
}